// Round 1
// baseline (229.548 us; speedup 1.0000x reference)
//
#include <hip/hip_runtime.h>
#include <math.h>

#define DEV __device__ __forceinline__

// ---------------- combo metadata ----------------
// combos (l, l1, l2) in reference order; sizes D*D1*D2; prefix offsets
__constant__ int C_L [11] = {0,0,0, 2,2,2,2, 4,4,4,4};
__constant__ int C_L1[11] = {0,2,4, 0,2,2,4, 0,2,2,4};
__constant__ int C_L2[11] = {0,2,4, 2,2,4,4, 4,2,4,4};
__constant__ int C_OFF[11]= {0,1,26,107,132,257,482,887,968,1193,1598};
// total CG floats per table = 2327; CGR at ws[0..2327), CGL at ws[2327..4654)

__constant__ double FACT[14] = {1.,1.,2.,6.,24.,120.,720.,5040.,40320.,362880.,
                                3628800.,39916800.,479001600.,6227020800.};

DEV int imax(int a, int b) { return a > b ? a : b; }
DEV int imin(int a, int b) { return a < b ? a : b; }

DEV double su2cg(int j1, int m1, int j2, int m2, int j3, int m3) {
  if (m3 != m1 + m2) return 0.0;
  int vmin = imax(imax(-j1 + j2 + m3, -j1 + m1), 0);
  int vmax = imin(imin(j2 + j3 + m1, j3 - j1 + j2), j3 + m3);
  if (vmax < vmin) return 0.0;
  double C = sqrt((2.0 * j3 + 1.0)
      * FACT[j3 + j1 - j2] * FACT[j3 - j1 + j2] * FACT[j1 + j2 - j3]
      * FACT[j3 + m3] * FACT[j3 - m3]
      / (FACT[j1 + j2 + j3 + 1] * FACT[j1 - m1] * FACT[j1 + m1]
         * FACT[j2 - m2] * FACT[j2 + m2]));
  double S = 0.0;
  for (int v = vmin; v <= vmax; ++v) {
    double term = FACT[j2 + j3 + m1 - v] * FACT[j1 - m1 + v]
        / (FACT[v] * FACT[j3 - j1 + j2 - v] * FACT[j3 + m3 - v]
           * FACT[v + j1 - j2 - m3]);
    S += ((v + j2 + m2) & 1) ? -term : term;
  }
  return C * S;
}

struct Cpx { double x, y; };

// nonzero entries of column c of e3nn's real->complex Q matrix for even l
// (factor (-i)^l is real: +1 for l%4==0, -1 for l%4==2)
DEV int qcol(int l, int c, int* rows, Cpx* vals) {
  const double r2 = 0.70710678118654752440;
  double sg = (l % 4 == 2) ? -1.0 : 1.0;
  if (c == l) { rows[0] = l; vals[0] = {sg, 0.0}; return 1; }
  if (c > l) {
    int mm = c - l;
    double par = (mm & 1) ? -1.0 : 1.0;
    rows[0] = l - mm; vals[0] = {sg * r2, 0.0};
    rows[1] = l + mm; vals[1] = {sg * par * r2, 0.0};
    return 2;
  }
  int mm = l - c;
  double par = (mm & 1) ? -1.0 : 1.0;
  rows[0] = l - mm; vals[0] = {0.0, -sg * r2};
  rows[1] = l + mm; vals[1] = {0.0, sg * par * r2};
  return 2;
}

// blocks 0..10: compute cg_r/cg_l tables for combo blockIdx.x into ws
// block 11: copy raw feats into the feats_out region of d_out
__global__ void cg_setup_kernel(float* __restrict__ ws,
                                const float* __restrict__ feats,
                                float* __restrict__ out) {
  int c = blockIdx.x;
  int tid = threadIdx.x;
  if (c == 11) {
    for (int i = tid; i < 1024; i += 256) {
      int n = i >> 6, j = i & 63;
      out[7012352 + n * 12352 + j] = feats[i];
    }
    return;
  }
  __shared__ double wbuf[729];
  __shared__ double red[256];
  const int l = C_L[c], l1 = C_L1[c], l2 = C_L2[c];
  const int D = 2 * l + 1, D1 = 2 * l1 + 1, D2 = 2 * l2 + 1;
  const int n = D * D1 * D2;
  const int off = C_OFF[c];

  // w[a][b][k] = Re( sum_{i,k2,n3} Q1[r1,a] Q2[r2,b] conj(Q3[r3,k]) C[r1,r2,r3] )
  for (int e = tid; e < n; e += 256) {
    int k = e % D; int ab = e / D; int b = ab % D2; int a = ab / D2;
    int r1[2], r2a[2], r3[2];
    Cpx v1[2], v2[2], v3[2];
    int n1 = qcol(l1, a, r1, v1);
    int n2 = qcol(l2, b, r2a, v2);
    int n3 = qcol(l, k, r3, v3);
    double s = 0.0;
    for (int i1 = 0; i1 < n1; ++i1) {
      for (int i2 = 0; i2 < n2; ++i2) {
        int m1 = r1[i1] - l1, m2 = r2a[i2] - l2;
        Cpx p12 = {v1[i1].x * v2[i2].x - v1[i1].y * v2[i2].y,
                   v1[i1].x * v2[i2].y + v1[i1].y * v2[i2].x};
        for (int i3 = 0; i3 < n3; ++i3) {
          int m3 = r3[i3] - l;
          if (m3 != m1 + m2) continue;
          double cg = su2cg(l1, m1, l2, m2, l, m3);
          if (cg == 0.0) continue;
          // Re(p12 * conj(v3))
          s += (p12.x * v3[i3].x + p12.y * v3[i3].y) * cg;
        }
      }
    }
    wbuf[e] = s;
  }
  __syncthreads();
  double part = 0.0;
  for (int e = tid; e < n; e += 256) part += wbuf[e] * wbuf[e];
  red[tid] = part;
  __syncthreads();
  for (int st = 128; st > 0; st >>= 1) {
    if (tid < st) red[tid] += red[tid + st];
    __syncthreads();
  }
  double scale = (l1 != l2) ? 1.41421356237309504880 : 1.0;
  double inv = scale / sqrt(red[0]);
  // cg (D,D2,D1) = transpose(w,(2,1,0)); cg_r = raw reshape to (D,D1,D2);
  // cg_l = transpose(cg_r,(0,2,1))
  for (int o = tid; o < n; o += 256) {
    int k = o / (D1 * D2); int t = o % (D1 * D2);
    int x = t / D2; int y = t % D2;     // cg_r[k][x][y]
    int a = t % D1; int b = t / D1;     // = w[a][b][k]
    float val = (float)(wbuf[(a * D2 + b) * D + k] * inv);
    ws[off + o] = val;                                  // CGR: k*D1*D2 + x*D2 + y
    ws[2327 + off + k * (D1 * D2) + y * D1 + x] = val;  // CGL: k*D1*D2 + y*D1 + x
  }
}

// ---------------- main compute ----------------
// LDS layout: lds[(elem)*65 + site], elem: 0 = rh0, 1..25 = rh2, 26..106 = rh4

template<int D, int D1, int D2>
DEV void run_combo(const float* __restrict__ cgr, const float* __restrict__ cgl,
                   const float* __restrict__ A, const float* __restrict__ B,
                   int lane, float* __restrict__ acc, int q0, int q1) {
  #pragma unroll 1
  for (int q = q0; q < q1; ++q) {
    float Brow[D2];
    #pragma unroll
    for (int j = 0; j < D2; ++j) Brow[j] = B[(q * D2 + j) * 65 + lane];
    const float* cglq = cgl + q * D1;
    #pragma unroll 1
    for (int p = 0; p < D1; ++p) {
      float Acol[D1];
      #pragma unroll
      for (int j = 0; j < D1; ++j) Acol[j] = A[(j * D1 + p) * 65 + lane];
      const float* cgrp = cgr + p * D2;
      float vl[D], vr[D];
      #pragma unroll
      for (int k = 0; k < D; ++k) {
        float s = 0.f;
        #pragma unroll
        for (int j = 0; j < D1; ++j) s = fmaf(Acol[j], cglq[k * D1 * D2 + j], s);
        vl[k] = s;
      }
      #pragma unroll
      for (int k = 0; k < D; ++k) {
        float s = 0.f;
        #pragma unroll
        for (int j = 0; j < D2; ++j) s = fmaf(Brow[j], cgrp[k * D1 * D2 + j], s);
        vr[k] = s;
      }
      #pragma unroll
      for (int k1 = 0; k1 < D; ++k1) {
        #pragma unroll
        for (int k2 = 0; k2 < D; ++k2)
          acc[k1 * D + k2] = fmaf(vl[k1], vr[k2], acc[k1 * D + k2]);
      }
    }
  }
}

__global__ __launch_bounds__(256, 2)
void quad_main(const float* __restrict__ rh0, const float* __restrict__ rh2,
               const float* __restrict__ rh4, const float* __restrict__ ws,
               float* __restrict__ out) {
  __shared__ float lds[107 * 65];
  const int tid = threadIdx.x;
  const int lane = tid & 63;
  const int wave = tid >> 6;
  const int blk = blockIdx.x;
  const int site0 = blk * 64;

  // stage 64 sites into LDS (coalesced global reads, conflict-free LDS writes)
  if (tid < 64) lds[tid] = rh0[site0 + tid];
  for (int f = tid; f < 1600; f += 256) {
    int s = f / 25, e = f - s * 25;
    lds[(1 + e) * 65 + s] = rh2[site0 * 25 + f];
  }
  for (int f = tid; f < 5184; f += 256) {
    int s = f / 81, e = f - s * 81;
    lds[(26 + e) * 65 + s] = rh4[site0 * 81 + f];
  }
  __syncthreads();

  const float* r0 = lds;
  const float* r2l = lds + 65;
  const float* r4l = lds + 26 * 65;
  const float* CGR = ws;
  const float* CGL = ws + 2327;

  float acc0[1] = {0.f};
  float acc2[25], acc4[81];
  #pragma unroll
  for (int i = 0; i < 25; ++i) acc2[i] = 0.f;
  #pragma unroll
  for (int i = 0; i < 81; ++i) acc4[i] = 0.f;

  // combo work split across the 4 waves (balanced ~ 11k-14k fma each)
  if (wave == 0) {
    run_combo<9,9,9>(CGR + 1598, CGL + 1598, r4l, r4l, lane, acc4, 0, 5);  // c10 part
  } else if (wave == 1) {
    run_combo<5,9,9>(CGR + 482, CGL + 482, r4l, r4l, lane, acc2, 0, 9);    // (2,4,4)
    run_combo<5,5,9>(CGR + 257, CGL + 257, r2l, r4l, lane, acc2, 0, 9);    // (2,2,4)
  } else if (wave == 2) {
    run_combo<9,5,9>(CGR + 1193, CGL + 1193, r2l, r4l, lane, acc4, 0, 9);  // (4,2,4)
    run_combo<9,5,5>(CGR + 968, CGL + 968, r2l, r2l, lane, acc4, 0, 5);    // (4,2,2)
  } else {
    run_combo<9,9,9>(CGR + 1598, CGL + 1598, r4l, r4l, lane, acc4, 5, 9);  // c10 rest
    run_combo<1,9,9>(CGR + 26, CGL + 26, r4l, r4l, lane, acc0, 0, 9);      // (0,4,4)
    run_combo<9,1,9>(CGR + 887, CGL + 887, r0, r4l, lane, acc4, 0, 9);     // (4,0,4)
    run_combo<5,5,5>(CGR + 132, CGL + 132, r2l, r2l, lane, acc2, 0, 5);    // (2,2,2)
    run_combo<5,1,5>(CGR + 107, CGL + 107, r0, r2l, lane, acc2, 0, 5);     // (2,0,2)
    run_combo<1,5,5>(CGR + 1, CGL + 1, r2l, r2l, lane, acc0, 0, 5);        // (0,2,2)
    run_combo<1,1,1>(CGR + 0, CGL + 0, r0, r0, lane, acc0, 0, 1);          // (0,0,0)
  }

  // merge partial accumulators through LDS (staging data is dead now)
  __syncthreads();
  if (wave == 0) {
    lds[lane] = acc0[0];
    #pragma unroll
    for (int e = 0; e < 25; ++e) lds[(1 + e) * 65 + lane] = acc2[e];
    #pragma unroll
    for (int e = 0; e < 81; ++e) lds[(26 + e) * 65 + lane] = acc4[e];
  }
  __syncthreads();
  if (wave == 1) {
    lds[lane] += acc0[0];
    #pragma unroll
    for (int e = 0; e < 25; ++e) lds[(1 + e) * 65 + lane] += acc2[e];
    #pragma unroll
    for (int e = 0; e < 81; ++e) lds[(26 + e) * 65 + lane] += acc4[e];
  }
  __syncthreads();
  if (wave == 2) {
    lds[lane] += acc0[0];
    #pragma unroll
    for (int e = 0; e < 25; ++e) lds[(1 + e) * 65 + lane] += acc2[e];
    #pragma unroll
    for (int e = 0; e < 81; ++e) lds[(26 + e) * 65 + lane] += acc4[e];
  }
  __syncthreads();
  if (wave == 3) {
    lds[lane] += acc0[0];
    #pragma unroll
    for (int e = 0; e < 25; ++e) lds[(1 + e) * 65 + lane] += acc2[e];
    #pragma unroll
    for (int e = 0; e < 81; ++e) lds[(26 + e) * 65 + lane] += acc4[e];
  }
  __syncthreads();

  // coalesced stores: rh_n[0] | rh_n[2] | rh_n[4]
  if (tid < 64) out[site0 + tid] = lds[tid];
  for (int f = tid; f < 1600; f += 256) {
    int s = f / 25, e = f - s * 25;
    out[65536 + blk * 1600 + f] = lds[(1 + e) * 65 + s];
  }
  for (int f = tid; f < 5184; f += 256) {
    int s = f / 81, e = f - s * 81;
    out[1703936 + blk * 5184 + f] = lds[(26 + e) * 65 + s];
  }

  // rotation-invariant features
  if (tid < 64) {
    int site = site0 + tid;
    int nn = site >> 12, abc = site & 4095;
    float v0 = lds[tid];
    float f0 = v0 * v0;
    float s2 = 0.f;
    #pragma unroll
    for (int e = 0; e < 25; ++e) { float v = lds[(1 + e) * 65 + tid]; s2 = fmaf(v, v, s2); }
    float s4 = 0.f;
    #pragma unroll
    for (int e = 0; e < 81; ++e) { float v = lds[(26 + e) * 65 + tid]; s4 = fmaf(v, v, s4); }
    const float PI8 = 78.95683520871486f;  // 8*pi^2
    int base = 7012352 + nn * 12352 + 64;
    out[base + abc] = PI8 * f0;
    out[base + 4096 + abc] = (PI8 / 5.f) * s2;
    out[base + 8192 + abc] = (PI8 / 9.f) * s4;
  }
}

extern "C" void kernel_launch(void* const* d_in, const int* in_sizes, int n_in,
                              void* d_out, int out_size, void* d_ws, size_t ws_size,
                              hipStream_t stream) {
  const float* rh0 = (const float*)d_in[0];
  const float* rh2 = (const float*)d_in[1];
  const float* rh4 = (const float*)d_in[2];
  const float* feats = (const float*)d_in[3];
  float* out = (float*)d_out;
  float* ws = (float*)d_ws;
  // CG tables -> d_ws (recomputed every call; ws is re-poisoned by harness)
  cg_setup_kernel<<<12, 256, 0, stream>>>(ws, feats, out);
  // main quadratic nonlinearity
  quad_main<<<1024, 256, 0, stream>>>(rh0, rh2, rh4, ws, out);
}